// Round 9
// baseline (152.779 us; speedup 1.0000x reference)
//
#include <hip/hip_runtime.h>
#include <hip/hip_fp16.h>

// Trilinear feature interpolation on a regular 65^3 vertex grid.
// R=64, SCALE=1.05, C=64, N=500000.
//
// R9 = R8 with ONE change: hipMemsetAsync(hist) -> own zero kernel.
// R8 post-mortem: the runtime's fillBufferAligned for the 128KB histogram
// zero ran at 74us (2 GB/s, ~10% occupancy) and was the LARGEST dispatch
// in the graph; the fine-binned sorted gather itself hit ~50us as
// predicted. Pipeline:
//   K0 : zero 32768-bin histogram (32 blocks, ~2us)
//   K1 : feats f32->f16 convert (streaming) + fine-bin histogram (2^3 cells)
//   K2 : one-block scan (1024 thr x 32 contiguous ints, Hillis-Steele)
//   K3 : scatter 16B records {x,y,z,orig} via cursor atomics
//   K4 : bin-sorted trilerp gather + bijective XCD-chunk swizzle
//        (consecutive records share cells/rows -> L1/L2 hits, ~3 line
//         requests/point instead of 8 = the measured serve-rate wall)

#define GRID_R     64
#define GRID_R1    65
#define NCHAN      64
#define NVERT      (GRID_R1 * GRID_R1 * GRID_R1)    // 274625
#define FEAT_ELEMS ((size_t)NVERT * NCHAN)          // 17,576,000 floats
#define NBIN2      32768                            // 32^3 bins (2-cell cube)

typedef float    f32x4 __attribute__((ext_vector_type(4)));
typedef int      i32x4 __attribute__((ext_vector_type(4)));
typedef _Float16 f16x8 __attribute__((ext_vector_type(8)));

__device__ __forceinline__ void cell_of(float px, float py, float pz,
                                        int& ci, int& cj, int& ck) {
    float x = (px / 2.1f + 0.5f) * 64.0f;
    float y = (py / 2.1f + 0.5f) * 64.0f;
    float z = (pz / 2.1f + 0.5f) * 64.0f;
    x = fminf(fmaxf(x, 0.0f), 64.0f);
    y = fminf(fmaxf(y, 0.0f), 64.0f);
    z = fminf(fmaxf(z, 0.0f), 64.0f);
    ci = min((int)x, GRID_R - 1);
    cj = min((int)y, GRID_R - 1);
    ck = min((int)z, GRID_R - 1);
}

__device__ __forceinline__ int bin_of(int ci, int cj, int ck) {
    return ((ci >> 1) << 10) | ((cj >> 1) << 5) | (ck >> 1);
}

// ---- K0: zero the histogram (replaces 74us runtime fillBuffer) ----
__global__ __launch_bounds__(256) void zero_hist_kernel(i32x4* __restrict__ hist4)
{
    // NBIN2 ints = 8192 i32x4; 32 blocks x 256 threads x 1 vec each
    int i = blockIdx.x * 256 + threadIdx.x;
    if (i < NBIN2 / 4) {
        i32x4 z = {0, 0, 0, 0};
        hist4[i] = z;
    }
}

// ---- K1: feats f32->f16 (streaming) + fine-bin point histogram ----
__global__ __launch_bounds__(256) void convert_hist_kernel(
    const f32x4* __restrict__ in,
    f16x8* __restrict__ outF,
    const float* __restrict__ pos,
    int* __restrict__ hist,          // [NBIN2]
    int n8, int n)
{
    int i = blockIdx.x * 256 + threadIdx.x;
    if (i < n8) {
        f32x4 a = __builtin_nontemporal_load(&in[2 * i]);
        f32x4 b = __builtin_nontemporal_load(&in[2 * i + 1]);
        f16x8 h;
        h[0] = (_Float16)a.x; h[1] = (_Float16)a.y;
        h[2] = (_Float16)a.z; h[3] = (_Float16)a.w;
        h[4] = (_Float16)b.x; h[5] = (_Float16)b.y;
        h[6] = (_Float16)b.z; h[7] = (_Float16)b.w;
        __builtin_nontemporal_store(h, &outF[i]);
    }
    if (i < n) {
        int ci, cj, ck;
        cell_of(pos[i * 3], pos[i * 3 + 1], pos[i * 3 + 2], ci, cj, ck);
        atomicAdd(&hist[bin_of(ci, cj, ck)], 1);
    }
}

// ---- K2: one-block exclusive scan of 32768 bins ----
__global__ __launch_bounds__(1024) void scan_kernel(
    const int* __restrict__ hist,    // [NBIN2]
    int* __restrict__ cursor)        // [NBIN2]
{
    __shared__ int s[1024];
    const int t = threadIdx.x;       // each thread owns 32 contiguous bins
    int pre[32];
    int tot = 0;
#pragma unroll
    for (int i = 0; i < 32; ++i) { pre[i] = tot; tot += hist[t * 32 + i]; }
    s[t] = tot;
    __syncthreads();
    for (int off = 1; off < 1024; off <<= 1) {
        int v = (t >= off) ? s[t - off] : 0;
        __syncthreads();
        s[t] += v;
        __syncthreads();
    }
    const int base = s[t] - tot;     // exclusive over the 1024 chunks
#pragma unroll
    for (int i = 0; i < 32; ++i) cursor[t * 32 + i] = base + pre[i];
}

// ---- K3: scatter sorted point records {px,py,pz,orig_idx} ----
__global__ __launch_bounds__(256) void scatter_kernel(
    const float* __restrict__ pos,
    int* __restrict__ cursor,        // [NBIN2]
    f32x4* __restrict__ records,
    int n)
{
    int i = blockIdx.x * 256 + threadIdx.x;
    if (i >= n) return;
    float px = pos[i * 3], py = pos[i * 3 + 1], pz = pos[i * 3 + 2];
    int ci, cj, ck;
    cell_of(px, py, pz, ci, cj, ck);
    int slot = atomicAdd(&cursor[bin_of(ci, cj, ck)], 1);
    f32x4 r = {px, py, pz, __int_as_float(i)};
    __builtin_nontemporal_store(r, &records[slot]);
}

// ---- K4: bin-sorted trilerp gather (fp16 table), XCD-chunked swizzle ----
__global__ __launch_bounds__(256) void trilerp_sorted_kernel(
    const f32x4* __restrict__ records,
    const f16x8* __restrict__ feats,
    f32x4* __restrict__ out4,
    int n, int nwg)
{
    const int o  = blockIdx.x;
    const int x  = o & 7, oo = o >> 3;
    const int q  = nwg >> 3, r = nwg & 7;
    const int vb = (x < r ? x * (q + 1) : r * (q + 1) + (x - r) * q) + oo;

    const int slot = vb * 32 + (threadIdx.x >> 3);  // 8 lanes per point
    if (slot >= n) return;
    const int sub = threadIdx.x & 7;

    const f32x4 rec = records[slot];
    const float px = rec.x, py = rec.y, pz = rec.z;
    const int orig = __float_as_int(rec.w);

    int ci, cj, ck;
    cell_of(px, py, pz, ci, cj, ck);

    const float INV_GS = 64.0f / 2.1f;
    float vx0 = ((float)ci       * 0.015625f - 0.5f) * 2.1f;
    float vx1 = ((float)(ci + 1) * 0.015625f - 0.5f) * 2.1f;
    float vy0 = ((float)cj       * 0.015625f - 0.5f) * 2.1f;
    float vy1 = ((float)(cj + 1) * 0.015625f - 0.5f) * 2.1f;
    float vz0 = ((float)ck       * 0.015625f - 0.5f) * 2.1f;
    float vz1 = ((float)(ck + 1) * 0.015625f - 0.5f) * 2.1f;

    // Corner (dx,dy,dz) weighted by distance to the OPPOSITE vertex.
    float wx1 = fabsf(px - vx0) * INV_GS;
    float wx0 = fabsf(px - vx1) * INV_GS;
    float wy1 = fabsf(py - vy0) * INV_GS;
    float wy0 = fabsf(py - vy1) * INV_GS;
    float wz1 = fabsf(pz - vz0) * INV_GS;
    float wz0 = fabsf(pz - vz1) * INV_GS;

    const int RS = NCHAN / 8;
    const int SY = GRID_R1 * RS;
    const int SX = GRID_R1 * GRID_R1 * RS;
    int base = ((ci * GRID_R1 + cj) * GRID_R1 + ck) * RS + sub;

    f16x8 f000 = feats[base];
    f16x8 f001 = feats[base + RS];
    f16x8 f010 = feats[base + SY];
    f16x8 f011 = feats[base + SY + RS];
    f16x8 f100 = feats[base + SX];
    f16x8 f101 = feats[base + SX + RS];
    f16x8 f110 = feats[base + SX + SY];
    f16x8 f111 = feats[base + SX + SY + RS];

    float w000 = wx0 * wy0 * wz0, w001 = wx0 * wy0 * wz1;
    float w010 = wx0 * wy1 * wz0, w011 = wx0 * wy1 * wz1;
    float w100 = wx1 * wy0 * wz0, w101 = wx1 * wy0 * wz1;
    float w110 = wx1 * wy1 * wz0, w111 = wx1 * wy1 * wz1;

    f32x4 acc0 = {0.f, 0.f, 0.f, 0.f};
    f32x4 acc1 = {0.f, 0.f, 0.f, 0.f};
#define ACCUM(F, W)                                                  \
    { acc0.x += (float)F[0] * W; acc0.y += (float)F[1] * W;          \
      acc0.z += (float)F[2] * W; acc0.w += (float)F[3] * W;          \
      acc1.x += (float)F[4] * W; acc1.y += (float)F[5] * W;          \
      acc1.z += (float)F[6] * W; acc1.w += (float)F[7] * W; }
    ACCUM(f000, w000) ACCUM(f001, w001) ACCUM(f010, w010) ACCUM(f011, w011)
    ACCUM(f100, w100) ACCUM(f101, w101) ACCUM(f110, w110) ACCUM(f111, w111)
#undef ACCUM

    __builtin_nontemporal_store(acc0, &out4[orig * 16 + sub * 2]);
    __builtin_nontemporal_store(acc1, &out4[orig * 16 + sub * 2 + 1]);
}

// ---- fallback: unsorted fp16 gather (medium ws) ----
__global__ __launch_bounds__(256) void trilerp_f16_kernel(
    const float* __restrict__ pos,
    const f16x8* __restrict__ feats,
    f32x4* __restrict__ out4,
    int n)
{
    const int tid = blockIdx.x * 256 + threadIdx.x;
    const int pt  = tid >> 3;
    if (pt >= n) return;
    const int sub = tid & 7;

    const float px = pos[pt * 3], py = pos[pt * 3 + 1], pz = pos[pt * 3 + 2];
    int ci, cj, ck;
    cell_of(px, py, pz, ci, cj, ck);

    const float INV_GS = 64.0f / 2.1f;
    float vx0 = ((float)ci       * 0.015625f - 0.5f) * 2.1f;
    float vx1 = ((float)(ci + 1) * 0.015625f - 0.5f) * 2.1f;
    float vy0 = ((float)cj       * 0.015625f - 0.5f) * 2.1f;
    float vy1 = ((float)(cj + 1) * 0.015625f - 0.5f) * 2.1f;
    float vz0 = ((float)ck       * 0.015625f - 0.5f) * 2.1f;
    float vz1 = ((float)(ck + 1) * 0.015625f - 0.5f) * 2.1f;

    float wx1 = fabsf(px - vx0) * INV_GS;
    float wx0 = fabsf(px - vx1) * INV_GS;
    float wy1 = fabsf(py - vy0) * INV_GS;
    float wy0 = fabsf(py - vy1) * INV_GS;
    float wz1 = fabsf(pz - vz0) * INV_GS;
    float wz0 = fabsf(pz - vz1) * INV_GS;

    const int RS = NCHAN / 8, SY = GRID_R1 * RS, SX = GRID_R1 * GRID_R1 * RS;
    int base = ((ci * GRID_R1 + cj) * GRID_R1 + ck) * RS + sub;

    f16x8 f000 = feats[base];
    f16x8 f001 = feats[base + RS];
    f16x8 f010 = feats[base + SY];
    f16x8 f011 = feats[base + SY + RS];
    f16x8 f100 = feats[base + SX];
    f16x8 f101 = feats[base + SX + RS];
    f16x8 f110 = feats[base + SX + SY];
    f16x8 f111 = feats[base + SX + SY + RS];

    float w000 = wx0 * wy0 * wz0, w001 = wx0 * wy0 * wz1;
    float w010 = wx0 * wy1 * wz0, w011 = wx0 * wy1 * wz1;
    float w100 = wx1 * wy0 * wz0, w101 = wx1 * wy0 * wz1;
    float w110 = wx1 * wy1 * wz0, w111 = wx1 * wy1 * wz1;

    f32x4 acc0 = {0.f, 0.f, 0.f, 0.f};
    f32x4 acc1 = {0.f, 0.f, 0.f, 0.f};
#define ACCUM(F, W)                                                  \
    { acc0.x += (float)F[0] * W; acc0.y += (float)F[1] * W;          \
      acc0.z += (float)F[2] * W; acc0.w += (float)F[3] * W;          \
      acc1.x += (float)F[4] * W; acc1.y += (float)F[5] * W;          \
      acc1.z += (float)F[6] * W; acc1.w += (float)F[7] * W; }
    ACCUM(f000, w000) ACCUM(f001, w001) ACCUM(f010, w010) ACCUM(f011, w011)
    ACCUM(f100, w100) ACCUM(f101, w101) ACCUM(f110, w110) ACCUM(f111, w111)
#undef ACCUM

    __builtin_nontemporal_store(acc0, &out4[pt * 16 + sub * 2]);
    __builtin_nontemporal_store(acc1, &out4[pt * 16 + sub * 2 + 1]);
}

// ---- fallback: direct f32 gather (tiny ws) ----
__global__ __launch_bounds__(256) void trilerp_f32_kernel(
    const float* __restrict__ pos,
    const f32x4* __restrict__ feats4,
    f32x4* __restrict__ out4,
    int n)
{
    const int tid = blockIdx.x * 256 + threadIdx.x;
    const int pt  = tid >> 4;
    if (pt >= n) return;
    const int sub = tid & 15;

    const float px = pos[pt * 3], py = pos[pt * 3 + 1], pz = pos[pt * 3 + 2];
    int ci, cj, ck;
    cell_of(px, py, pz, ci, cj, ck);

    const float INV_GS = 64.0f / 2.1f;
    float vx0 = ((float)ci       * 0.015625f - 0.5f) * 2.1f;
    float vx1 = ((float)(ci + 1) * 0.015625f - 0.5f) * 2.1f;
    float vy0 = ((float)cj       * 0.015625f - 0.5f) * 2.1f;
    float vy1 = ((float)(cj + 1) * 0.015625f - 0.5f) * 2.1f;
    float vz0 = ((float)ck       * 0.015625f - 0.5f) * 2.1f;
    float vz1 = ((float)(ck + 1) * 0.015625f - 0.5f) * 2.1f;

    float wx1 = fabsf(px - vx0) * INV_GS, wx0 = fabsf(px - vx1) * INV_GS;
    float wy1 = fabsf(py - vy0) * INV_GS, wy0 = fabsf(py - vy1) * INV_GS;
    float wz1 = fabsf(pz - vz0) * INV_GS, wz0 = fabsf(pz - vz1) * INV_GS;
    float w[8] = {wx0*wy0*wz0, wx0*wy0*wz1, wx0*wy1*wz0, wx0*wy1*wz1,
                  wx1*wy0*wz0, wx1*wy0*wz1, wx1*wy1*wz0, wx1*wy1*wz1};

    const int RS = 16, SY = GRID_R1 * RS, SX = GRID_R1 * GRID_R1 * RS;
    const int off[8] = {0, RS, SY, SY + RS, SX, SX + RS, SX + SY, SX + SY + RS};
    int b = ((ci * GRID_R1 + cj) * GRID_R1 + ck) * 16 + sub;

    f32x4 acc = {0.f, 0.f, 0.f, 0.f};
#pragma unroll
    for (int c = 0; c < 8; ++c) acc += feats4[b + off[c]] * w[c];

    __builtin_nontemporal_store(acc, &out4[pt * 16 + sub]);
}

extern "C" void kernel_launch(void* const* d_in, const int* in_sizes, int n_in,
                              void* d_out, int out_size, void* d_ws, size_t ws_size,
                              hipStream_t stream) {
    const float* pos   = (const float*)d_in[0];
    const float* feats = (const float*)d_in[1];
    // d_in[2] (vertices) and d_in[3] (grid_indices) recomputed analytically.
    f32x4* out4 = (f32x4*)d_out;

    const int n  = in_sizes[0] / 3;                 // 500000
    const int n8 = (int)(FEAT_ELEMS / 8);           // 2,197,000

    const size_t featBytes = FEAT_ELEMS * sizeof(_Float16);      // 35.15 MB
    const size_t offF = 0;
    const size_t offR = (featBytes + 127) & ~(size_t)127;        // records
    const size_t offH = offR + (size_t)n * 16;                   // hist
    const size_t offC = offH + (size_t)NBIN2 * sizeof(int);      // cursor
    const size_t needSorted = offC + (size_t)NBIN2 * sizeof(int);

    if (ws_size >= needSorted) {
        char* ws = (char*)d_ws;
        f16x8* feats16 = (f16x8*)(ws + offF);
        f32x4* records = (f32x4*)(ws + offR);
        int*   hist    = (int*)(ws + offH);
        int*   cursor  = (int*)(ws + offC);

        zero_hist_kernel<<<NBIN2 / 4 / 256, 256, 0, stream>>>((i32x4*)hist);

        convert_hist_kernel<<<(n8 + 255) / 256, 256, 0, stream>>>(
            (const f32x4*)feats, feats16, pos, hist, n8, n);

        scan_kernel<<<1, 1024, 0, stream>>>(hist, cursor);

        scatter_kernel<<<(n + 255) / 256, 256, 0, stream>>>(
            pos, cursor, records, n);

        const int nwg = (n + 31) / 32;
        trilerp_sorted_kernel<<<nwg, 256, 0, stream>>>(
            records, feats16, out4, n, nwg);
    } else if (ws_size >= featBytes) {
        f16x8* feats16 = (f16x8*)d_ws;
        convert_hist_kernel<<<(n8 + 255) / 256, 256, 0, stream>>>(
            (const f32x4*)feats, feats16, nullptr, nullptr, n8, 0);
        const long long total = (long long)n * 8;
        trilerp_f16_kernel<<<(int)((total + 255) / 256), 256, 0, stream>>>(
            pos, feats16, out4, n);
    } else {
        const long long total = (long long)n * 16;
        trilerp_f32_kernel<<<(int)((total + 255) / 256), 256, 0, stream>>>(
            pos, (const f32x4*)feats, out4, n);
    }
}

// Round 10
// 144.936 us; speedup vs baseline: 1.0541x; 1.0541x over previous
//
#include <hip/hip_runtime.h>
#include <hip/hip_fp16.h>

// Trilinear feature interpolation on a regular 65^3 vertex grid.
// R=64, SCALE=1.05, C=64, N=500000.
//
// R10 sorted pipeline, prep minimized:
//   K0 : zero 32768-bin histogram (own kernel, 32 blocks)
//   K1 : feats f32->f16 convert (streaming) + fine-bin histogram (2^3 cells,
//        500k atomics / 32k bins ~ 15/addr, contention-safe)
//   K2 : one-block scan, IN-PLACE (cursor written over hist; each thread
//        reads its 32 contiguous bins before any writes -> safe)
//   K3 : scatter 16B records {x,y,z,orig} -- PLAIN stores (consumed by K4;
//        R8/R9's nontemporal pushed them out of L2)
//   K4 : bin-sorted trilerp gather + bijective XCD-chunk swizzle.
//        32 pts/block span ~2 bins (~7KB rows) -> L1 hits; this removes the
//        512MB random L1-refill stream that pins the unsorted gather at
//        93us (6.9 TB/s = streaming ceiling).

#define GRID_R     64
#define GRID_R1    65
#define NCHAN      64
#define NVERT      (GRID_R1 * GRID_R1 * GRID_R1)    // 274625
#define FEAT_ELEMS ((size_t)NVERT * NCHAN)          // 17,576,000 floats
#define NBIN2      32768                            // 32^3 bins (2-cell cube)

typedef float    f32x4 __attribute__((ext_vector_type(4)));
typedef int      i32x4 __attribute__((ext_vector_type(4)));
typedef _Float16 f16x8 __attribute__((ext_vector_type(8)));

__device__ __forceinline__ void cell_of(float px, float py, float pz,
                                        int& ci, int& cj, int& ck) {
    float x = (px / 2.1f + 0.5f) * 64.0f;
    float y = (py / 2.1f + 0.5f) * 64.0f;
    float z = (pz / 2.1f + 0.5f) * 64.0f;
    x = fminf(fmaxf(x, 0.0f), 64.0f);
    y = fminf(fmaxf(y, 0.0f), 64.0f);
    z = fminf(fmaxf(z, 0.0f), 64.0f);
    ci = min((int)x, GRID_R - 1);
    cj = min((int)y, GRID_R - 1);
    ck = min((int)z, GRID_R - 1);
}

__device__ __forceinline__ int bin_of(int ci, int cj, int ck) {
    return ((ci >> 1) << 10) | ((cj >> 1) << 5) | (ck >> 1);
}

// ---- K0: zero the histogram ----
__global__ __launch_bounds__(256) void zero_hist_kernel(i32x4* __restrict__ hist4)
{
    int i = blockIdx.x * 256 + threadIdx.x;
    if (i < NBIN2 / 4) {
        i32x4 z = {0, 0, 0, 0};
        hist4[i] = z;
    }
}

// ---- K1: feats f32->f16 (streaming) + fine-bin point histogram ----
__global__ __launch_bounds__(256) void convert_hist_kernel(
    const f32x4* __restrict__ in,
    f16x8* __restrict__ outF,
    const float* __restrict__ pos,
    int* __restrict__ hist,          // [NBIN2]
    int n8, int n)
{
    int i = blockIdx.x * 256 + threadIdx.x;
    if (i < n8) {
        f32x4 a = __builtin_nontemporal_load(&in[2 * i]);
        f32x4 b = __builtin_nontemporal_load(&in[2 * i + 1]);
        f16x8 h;
        h[0] = (_Float16)a.x; h[1] = (_Float16)a.y;
        h[2] = (_Float16)a.z; h[3] = (_Float16)a.w;
        h[4] = (_Float16)b.x; h[5] = (_Float16)b.y;
        h[6] = (_Float16)b.z; h[7] = (_Float16)b.w;
        __builtin_nontemporal_store(h, &outF[i]);
    }
    if (i < n) {
        int ci, cj, ck;
        cell_of(pos[i * 3], pos[i * 3 + 1], pos[i * 3 + 2], ci, cj, ck);
        atomicAdd(&hist[bin_of(ci, cj, ck)], 1);
    }
}

// ---- K2: one-block exclusive scan of 32768 bins, IN-PLACE ----
// Safe in-place: each thread reads its 32 contiguous bins entirely before
// the LDS phase; writes happen only after, to the same 32 slots.
__global__ __launch_bounds__(1024) void scan_kernel(int* __restrict__ buf)
{
    __shared__ int s[1024];
    const int t = threadIdx.x;       // each thread owns 32 contiguous bins
    int pre[32];
    int tot = 0;
#pragma unroll
    for (int i = 0; i < 32; ++i) { pre[i] = tot; tot += buf[t * 32 + i]; }
    s[t] = tot;
    __syncthreads();
    for (int off = 1; off < 1024; off <<= 1) {
        int v = (t >= off) ? s[t - off] : 0;
        __syncthreads();
        s[t] += v;
        __syncthreads();
    }
    const int base = s[t] - tot;     // exclusive over the 1024 chunks
#pragma unroll
    for (int i = 0; i < 32; ++i) buf[t * 32 + i] = base + pre[i];
}

// ---- K3: scatter sorted point records {px,py,pz,orig_idx} ----
__global__ __launch_bounds__(256) void scatter_kernel(
    const float* __restrict__ pos,
    int* __restrict__ cursor,        // [NBIN2] (the scanned buffer)
    f32x4* __restrict__ records,
    int n)
{
    int i = blockIdx.x * 256 + threadIdx.x;
    if (i >= n) return;
    float px = pos[i * 3], py = pos[i * 3 + 1], pz = pos[i * 3 + 2];
    int ci, cj, ck;
    cell_of(px, py, pz, ci, cj, ck);
    int slot = atomicAdd(&cursor[bin_of(ci, cj, ck)], 1);
    f32x4 r = {px, py, pz, __int_as_float(i)};
    records[slot] = r;               // PLAIN store: K4 reads these next
}

// ---- K4: bin-sorted trilerp gather (fp16 table), XCD-chunked swizzle ----
__global__ __launch_bounds__(256) void trilerp_sorted_kernel(
    const f32x4* __restrict__ records,
    const f16x8* __restrict__ feats,
    f32x4* __restrict__ out4,
    int n, int nwg)
{
    const int o  = blockIdx.x;
    const int x  = o & 7, oo = o >> 3;
    const int q  = nwg >> 3, r = nwg & 7;
    const int vb = (x < r ? x * (q + 1) : r * (q + 1) + (x - r) * q) + oo;

    const int slot = vb * 32 + (threadIdx.x >> 3);  // 8 lanes per point
    if (slot >= n) return;
    const int sub = threadIdx.x & 7;

    const f32x4 rec = records[slot];
    const float px = rec.x, py = rec.y, pz = rec.z;
    const int orig = __float_as_int(rec.w);

    int ci, cj, ck;
    cell_of(px, py, pz, ci, cj, ck);

    const float INV_GS = 64.0f / 2.1f;
    float vx0 = ((float)ci       * 0.015625f - 0.5f) * 2.1f;
    float vx1 = ((float)(ci + 1) * 0.015625f - 0.5f) * 2.1f;
    float vy0 = ((float)cj       * 0.015625f - 0.5f) * 2.1f;
    float vy1 = ((float)(cj + 1) * 0.015625f - 0.5f) * 2.1f;
    float vz0 = ((float)ck       * 0.015625f - 0.5f) * 2.1f;
    float vz1 = ((float)(ck + 1) * 0.015625f - 0.5f) * 2.1f;

    // Corner (dx,dy,dz) weighted by distance to the OPPOSITE vertex.
    float wx1 = fabsf(px - vx0) * INV_GS;
    float wx0 = fabsf(px - vx1) * INV_GS;
    float wy1 = fabsf(py - vy0) * INV_GS;
    float wy0 = fabsf(py - vy1) * INV_GS;
    float wz1 = fabsf(pz - vz0) * INV_GS;
    float wz0 = fabsf(pz - vz1) * INV_GS;

    const int RS = NCHAN / 8;
    const int SY = GRID_R1 * RS;
    const int SX = GRID_R1 * GRID_R1 * RS;
    int base = ((ci * GRID_R1 + cj) * GRID_R1 + ck) * RS + sub;

    f16x8 f000 = feats[base];
    f16x8 f001 = feats[base + RS];
    f16x8 f010 = feats[base + SY];
    f16x8 f011 = feats[base + SY + RS];
    f16x8 f100 = feats[base + SX];
    f16x8 f101 = feats[base + SX + RS];
    f16x8 f110 = feats[base + SX + SY];
    f16x8 f111 = feats[base + SX + SY + RS];

    float w000 = wx0 * wy0 * wz0, w001 = wx0 * wy0 * wz1;
    float w010 = wx0 * wy1 * wz0, w011 = wx0 * wy1 * wz1;
    float w100 = wx1 * wy0 * wz0, w101 = wx1 * wy0 * wz1;
    float w110 = wx1 * wy1 * wz0, w111 = wx1 * wy1 * wz1;

    f32x4 acc0 = {0.f, 0.f, 0.f, 0.f};
    f32x4 acc1 = {0.f, 0.f, 0.f, 0.f};
#define ACCUM(F, W)                                                  \
    { acc0.x += (float)F[0] * W; acc0.y += (float)F[1] * W;          \
      acc0.z += (float)F[2] * W; acc0.w += (float)F[3] * W;          \
      acc1.x += (float)F[4] * W; acc1.y += (float)F[5] * W;          \
      acc1.z += (float)F[6] * W; acc1.w += (float)F[7] * W; }
    ACCUM(f000, w000) ACCUM(f001, w001) ACCUM(f010, w010) ACCUM(f011, w011)
    ACCUM(f100, w100) ACCUM(f101, w101) ACCUM(f110, w110) ACCUM(f111, w111)
#undef ACCUM

    __builtin_nontemporal_store(acc0, &out4[orig * 16 + sub * 2]);
    __builtin_nontemporal_store(acc1, &out4[orig * 16 + sub * 2 + 1]);
}

// ---- fallback: unsorted fp16 gather (medium ws) ----
__global__ __launch_bounds__(256) void trilerp_f16_kernel(
    const float* __restrict__ pos,
    const f16x8* __restrict__ feats,
    f32x4* __restrict__ out4,
    int n)
{
    const int tid = blockIdx.x * 256 + threadIdx.x;
    const int pt  = tid >> 3;
    if (pt >= n) return;
    const int sub = tid & 7;

    const float px = pos[pt * 3], py = pos[pt * 3 + 1], pz = pos[pt * 3 + 2];
    int ci, cj, ck;
    cell_of(px, py, pz, ci, cj, ck);

    const float INV_GS = 64.0f / 2.1f;
    float vx0 = ((float)ci       * 0.015625f - 0.5f) * 2.1f;
    float vx1 = ((float)(ci + 1) * 0.015625f - 0.5f) * 2.1f;
    float vy0 = ((float)cj       * 0.015625f - 0.5f) * 2.1f;
    float vy1 = ((float)(cj + 1) * 0.015625f - 0.5f) * 2.1f;
    float vz0 = ((float)ck       * 0.015625f - 0.5f) * 2.1f;
    float vz1 = ((float)(ck + 1) * 0.015625f - 0.5f) * 2.1f;

    float wx1 = fabsf(px - vx0) * INV_GS;
    float wx0 = fabsf(px - vx1) * INV_GS;
    float wy1 = fabsf(py - vy0) * INV_GS;
    float wy0 = fabsf(py - vy1) * INV_GS;
    float wz1 = fabsf(pz - vz0) * INV_GS;
    float wz0 = fabsf(pz - vz1) * INV_GS;

    const int RS = NCHAN / 8, SY = GRID_R1 * RS, SX = GRID_R1 * GRID_R1 * RS;
    int base = ((ci * GRID_R1 + cj) * GRID_R1 + ck) * RS + sub;

    f16x8 f000 = feats[base];
    f16x8 f001 = feats[base + RS];
    f16x8 f010 = feats[base + SY];
    f16x8 f011 = feats[base + SY + RS];
    f16x8 f100 = feats[base + SX];
    f16x8 f101 = feats[base + SX + RS];
    f16x8 f110 = feats[base + SX + SY];
    f16x8 f111 = feats[base + SX + SY + RS];

    float w000 = wx0 * wy0 * wz0, w001 = wx0 * wy0 * wz1;
    float w010 = wx0 * wy1 * wz0, w011 = wx0 * wy1 * wz1;
    float w100 = wx1 * wy0 * wz0, w101 = wx1 * wy0 * wz1;
    float w110 = wx1 * wy1 * wz0, w111 = wx1 * wy1 * wz1;

    f32x4 acc0 = {0.f, 0.f, 0.f, 0.f};
    f32x4 acc1 = {0.f, 0.f, 0.f, 0.f};
#define ACCUM(F, W)                                                  \
    { acc0.x += (float)F[0] * W; acc0.y += (float)F[1] * W;          \
      acc0.z += (float)F[2] * W; acc0.w += (float)F[3] * W;          \
      acc1.x += (float)F[4] * W; acc1.y += (float)F[5] * W;          \
      acc1.z += (float)F[6] * W; acc1.w += (float)F[7] * W; }
    ACCUM(f000, w000) ACCUM(f001, w001) ACCUM(f010, w010) ACCUM(f011, w011)
    ACCUM(f100, w100) ACCUM(f101, w101) ACCUM(f110, w110) ACCUM(f111, w111)
#undef ACCUM

    __builtin_nontemporal_store(acc0, &out4[pt * 16 + sub * 2]);
    __builtin_nontemporal_store(acc1, &out4[pt * 16 + sub * 2 + 1]);
}

// ---- fallback: direct f32 gather (tiny ws) ----
__global__ __launch_bounds__(256) void trilerp_f32_kernel(
    const float* __restrict__ pos,
    const f32x4* __restrict__ feats4,
    f32x4* __restrict__ out4,
    int n)
{
    const int tid = blockIdx.x * 256 + threadIdx.x;
    const int pt  = tid >> 4;
    if (pt >= n) return;
    const int sub = tid & 15;

    const float px = pos[pt * 3], py = pos[pt * 3 + 1], pz = pos[pt * 3 + 2];
    int ci, cj, ck;
    cell_of(px, py, pz, ci, cj, ck);

    const float INV_GS = 64.0f / 2.1f;
    float vx0 = ((float)ci       * 0.015625f - 0.5f) * 2.1f;
    float vx1 = ((float)(ci + 1) * 0.015625f - 0.5f) * 2.1f;
    float vy0 = ((float)cj       * 0.015625f - 0.5f) * 2.1f;
    float vy1 = ((float)(cj + 1) * 0.015625f - 0.5f) * 2.1f;
    float vz0 = ((float)ck       * 0.015625f - 0.5f) * 2.1f;
    float vz1 = ((float)(ck + 1) * 0.015625f - 0.5f) * 2.1f;

    float wx1 = fabsf(px - vx0) * INV_GS, wx0 = fabsf(px - vx1) * INV_GS;
    float wy1 = fabsf(py - vy0) * INV_GS, wy0 = fabsf(py - vy1) * INV_GS;
    float wz1 = fabsf(pz - vz0) * INV_GS, wz0 = fabsf(pz - vz1) * INV_GS;
    float w[8] = {wx0*wy0*wz0, wx0*wy0*wz1, wx0*wy1*wz0, wx0*wy1*wz1,
                  wx1*wy0*wz0, wx1*wy0*wz1, wx1*wy1*wz0, wx1*wy1*wz1};

    const int RS = 16, SY = GRID_R1 * RS, SX = GRID_R1 * GRID_R1 * RS;
    const int off[8] = {0, RS, SY, SY + RS, SX, SX + RS, SX + SY, SX + SY + RS};
    int b = ((ci * GRID_R1 + cj) * GRID_R1 + ck) * 16 + sub;

    f32x4 acc = {0.f, 0.f, 0.f, 0.f};
#pragma unroll
    for (int c = 0; c < 8; ++c) acc += feats4[b + off[c]] * w[c];

    __builtin_nontemporal_store(acc, &out4[pt * 16 + sub]);
}

extern "C" void kernel_launch(void* const* d_in, const int* in_sizes, int n_in,
                              void* d_out, int out_size, void* d_ws, size_t ws_size,
                              hipStream_t stream) {
    const float* pos   = (const float*)d_in[0];
    const float* feats = (const float*)d_in[1];
    // d_in[2] (vertices) and d_in[3] (grid_indices) recomputed analytically.
    f32x4* out4 = (f32x4*)d_out;

    const int n  = in_sizes[0] / 3;                 // 500000
    const int n8 = (int)(FEAT_ELEMS / 8);           // 2,197,000

    const size_t featBytes = FEAT_ELEMS * sizeof(_Float16);      // 35.15 MB
    const size_t offF = 0;
    const size_t offR = (featBytes + 127) & ~(size_t)127;        // records
    const size_t offH = offR + (size_t)n * 16;                   // hist/cursor
    const size_t needSorted = offH + (size_t)NBIN2 * sizeof(int);

    if (ws_size >= needSorted) {
        char* ws = (char*)d_ws;
        f16x8* feats16 = (f16x8*)(ws + offF);
        f32x4* records = (f32x4*)(ws + offR);
        int*   hist    = (int*)(ws + offH);      // scanned in-place -> cursor

        zero_hist_kernel<<<NBIN2 / 4 / 256, 256, 0, stream>>>((i32x4*)hist);

        convert_hist_kernel<<<(n8 + 255) / 256, 256, 0, stream>>>(
            (const f32x4*)feats, feats16, pos, hist, n8, n);

        scan_kernel<<<1, 1024, 0, stream>>>(hist);

        scatter_kernel<<<(n + 255) / 256, 256, 0, stream>>>(
            pos, hist, records, n);

        const int nwg = (n + 31) / 32;
        trilerp_sorted_kernel<<<nwg, 256, 0, stream>>>(
            records, feats16, out4, n, nwg);
    } else if (ws_size >= featBytes) {
        f16x8* feats16 = (f16x8*)d_ws;
        convert_hist_kernel<<<(n8 + 255) / 256, 256, 0, stream>>>(
            (const f32x4*)feats, feats16, nullptr, nullptr, n8, 0);
        const long long total = (long long)n * 8;
        trilerp_f16_kernel<<<(int)((total + 255) / 256), 256, 0, stream>>>(
            pos, feats16, out4, n);
    } else {
        const long long total = (long long)n * 16;
        trilerp_f32_kernel<<<(int)((total + 255) / 256), 256, 0, stream>>>(
            pos, (const f32x4*)feats, out4, n);
    }
}

// Round 11
// 112.860 us; speedup vs baseline: 1.3537x; 1.2842x over previous
//
#include <hip/hip_runtime.h>
#include <hip/hip_fp16.h>

// Trilinear feature interpolation on a regular 65^3 vertex grid.
// R=64, SCALE=1.05, C=64, N=500000.
//
// R11 = revert to the R4 two-kernel pipeline (best measured: 108.4us).
//   K1: feats f32->f16 into d_ws (105 MB streaming, ~15us, at BW roofline)
//   K2: unsorted gather, 8 lanes/point, 8x 16B feat loads in flight,
//       nontemporal 256B/point output (~93us).
// Why this is the stopping point (measured across R5-R10):
//  - Unsorted gather floor: 500k x 8 distinct 128B lines = 512MB of
//    compulsory L1-refill traffic (random order, no reuse) + 128MB writes
//    ~= 6.9 TB/s effective in 93us = streaming ceiling. ILP x2 (R7): no
//    change. fp8 table would halve bytes but breaks the 8.3e-5 threshold.
//  - Spatial-sort pipelines DO fix locality (sorted gather 78us, FETCH
//    225->23MB) but prep kernels + multi-kernel graph overhead cost more
//    than the 15us saved (best sorted total: 127us vs 108 here).

#define GRID_R     64
#define GRID_R1    65
#define NCHAN      64
#define NVERT      (GRID_R1 * GRID_R1 * GRID_R1)    // 274625
#define FEAT_ELEMS ((size_t)NVERT * NCHAN)          // 17,576,000 floats

typedef float    f32x4 __attribute__((ext_vector_type(4)));
typedef _Float16 f16x8 __attribute__((ext_vector_type(8)));

__device__ __forceinline__ void cell_of(float px, float py, float pz,
                                        int& ci, int& cj, int& ck) {
    float x = (px / 2.1f + 0.5f) * 64.0f;
    float y = (py / 2.1f + 0.5f) * 64.0f;
    float z = (pz / 2.1f + 0.5f) * 64.0f;
    x = fminf(fmaxf(x, 0.0f), 64.0f);
    y = fminf(fmaxf(y, 0.0f), 64.0f);
    z = fminf(fmaxf(z, 0.0f), 64.0f);
    ci = min((int)x, GRID_R - 1);
    cj = min((int)y, GRID_R - 1);
    ck = min((int)z, GRID_R - 1);
}

// ---- pass 1: feats f32 -> f16 (streaming, ~105 MB of traffic) ----
__global__ __launch_bounds__(256) void convert_kernel(
    const f32x4* __restrict__ in,   // feats as f32x4, 2 per output f16x8
    f16x8* __restrict__ out,
    int n8)                          // FEAT_ELEMS / 8
{
    int i = blockIdx.x * 256 + threadIdx.x;
    if (i >= n8) return;
    f32x4 a = __builtin_nontemporal_load(&in[2 * i]);
    f32x4 b = __builtin_nontemporal_load(&in[2 * i + 1]);
    f16x8 h;
    h[0] = (_Float16)a.x; h[1] = (_Float16)a.y;
    h[2] = (_Float16)a.z; h[3] = (_Float16)a.w;
    h[4] = (_Float16)b.x; h[5] = (_Float16)b.y;
    h[6] = (_Float16)b.z; h[7] = (_Float16)b.w;
    __builtin_nontemporal_store(h, &out[i]);
}

// ---- pass 2: trilerp gather from fp16 table, 8 lanes per point ----
__global__ __launch_bounds__(256) void trilerp_f16_kernel(
    const float* __restrict__ pos,    // [n,3]
    const f16x8* __restrict__ feats,  // [65^3, 8] f16x8 (64 ch per row)
    f32x4* __restrict__ out4,         // [n,16] f32x4
    int n)
{
    const int tid = blockIdx.x * 256 + threadIdx.x;
    const int pt  = tid >> 3;          // 8 lanes per point
    if (pt >= n) return;
    const int sub = tid & 7;           // which f16x8 (8 channels) of the row

    const float px = pos[pt * 3 + 0];
    const float py = pos[pt * 3 + 1];
    const float pz = pos[pt * 3 + 2];

    int ci, cj, ck;
    cell_of(px, py, pz, ci, cj, ck);

    // Vertex coords: v(a) = (a * 2^-6 - 0.5) * 2.1 (bit-matches numpy table)
    const float INV_GS = 64.0f / 2.1f;
    float vx0 = ((float)ci       * 0.015625f - 0.5f) * 2.1f;
    float vx1 = ((float)(ci + 1) * 0.015625f - 0.5f) * 2.1f;
    float vy0 = ((float)cj       * 0.015625f - 0.5f) * 2.1f;
    float vy1 = ((float)(cj + 1) * 0.015625f - 0.5f) * 2.1f;
    float vz0 = ((float)ck       * 0.015625f - 0.5f) * 2.1f;
    float vz1 = ((float)(ck + 1) * 0.015625f - 0.5f) * 2.1f;

    // Corner (dx,dy,dz) weighted by distance to the OPPOSITE vertex.
    float wx1 = fabsf(px - vx0) * INV_GS;
    float wx0 = fabsf(px - vx1) * INV_GS;
    float wy1 = fabsf(py - vy0) * INV_GS;
    float wy0 = fabsf(py - vy1) * INV_GS;
    float wz1 = fabsf(pz - vz0) * INV_GS;
    float wz0 = fabsf(pz - vz1) * INV_GS;

    // Row = 64 ch = 8 f16x8 units. 8 lanes cover the 128B row.
    const int RS = NCHAN / 8;                 // 8 units per row
    const int SY = GRID_R1 * RS;              // +1 in j
    const int SX = GRID_R1 * GRID_R1 * RS;    // +1 in i
    int base = ((ci * GRID_R1 + cj) * GRID_R1 + ck) * RS + sub;

    // Issue all 8 gathers up front (8x dwordx4 in flight per lane).
    f16x8 f000 = feats[base];
    f16x8 f001 = feats[base + RS];
    f16x8 f010 = feats[base + SY];
    f16x8 f011 = feats[base + SY + RS];
    f16x8 f100 = feats[base + SX];
    f16x8 f101 = feats[base + SX + RS];
    f16x8 f110 = feats[base + SX + SY];
    f16x8 f111 = feats[base + SX + SY + RS];

    float w000 = wx0 * wy0 * wz0, w001 = wx0 * wy0 * wz1;
    float w010 = wx0 * wy1 * wz0, w011 = wx0 * wy1 * wz1;
    float w100 = wx1 * wy0 * wz0, w101 = wx1 * wy0 * wz1;
    float w110 = wx1 * wy1 * wz0, w111 = wx1 * wy1 * wz1;

    f32x4 acc0 = {0.f, 0.f, 0.f, 0.f};
    f32x4 acc1 = {0.f, 0.f, 0.f, 0.f};
#define ACCUM(F, W)                                                  \
    { acc0.x += (float)F[0] * W; acc0.y += (float)F[1] * W;          \
      acc0.z += (float)F[2] * W; acc0.w += (float)F[3] * W;          \
      acc1.x += (float)F[4] * W; acc1.y += (float)F[5] * W;          \
      acc1.z += (float)F[6] * W; acc1.w += (float)F[7] * W; }
    ACCUM(f000, w000) ACCUM(f001, w001) ACCUM(f010, w010) ACCUM(f011, w011)
    ACCUM(f100, w100) ACCUM(f101, w101) ACCUM(f110, w110) ACCUM(f111, w111)
#undef ACCUM

    // Each lane owns channels [sub*8, sub*8+8): two f32x4 stores, row coalesced.
    // Write-once output: nontemporal so it doesn't evict the feats table.
    __builtin_nontemporal_store(acc0, &out4[pt * 16 + sub * 2]);
    __builtin_nontemporal_store(acc1, &out4[pt * 16 + sub * 2 + 1]);
}

// ---- fallback: direct f32 gather (if d_ws too small for the f16 table) ----
__global__ __launch_bounds__(256) void trilerp_f32_kernel(
    const float* __restrict__ pos,
    const f32x4* __restrict__ feats4,
    f32x4* __restrict__ out4,
    int n)
{
    const int tid = blockIdx.x * 256 + threadIdx.x;
    const int pt  = tid >> 4;
    if (pt >= n) return;
    const int sub = tid & 15;

    const float px = pos[pt * 3], py = pos[pt * 3 + 1], pz = pos[pt * 3 + 2];
    int ci, cj, ck;
    cell_of(px, py, pz, ci, cj, ck);

    const float INV_GS = 64.0f / 2.1f;
    float vx0 = ((float)ci       * 0.015625f - 0.5f) * 2.1f;
    float vx1 = ((float)(ci + 1) * 0.015625f - 0.5f) * 2.1f;
    float vy0 = ((float)cj       * 0.015625f - 0.5f) * 2.1f;
    float vy1 = ((float)(cj + 1) * 0.015625f - 0.5f) * 2.1f;
    float vz0 = ((float)ck       * 0.015625f - 0.5f) * 2.1f;
    float vz1 = ((float)(ck + 1) * 0.015625f - 0.5f) * 2.1f;

    float wx1 = fabsf(px - vx0) * INV_GS, wx0 = fabsf(px - vx1) * INV_GS;
    float wy1 = fabsf(py - vy0) * INV_GS, wy0 = fabsf(py - vy1) * INV_GS;
    float wz1 = fabsf(pz - vz0) * INV_GS, wz0 = fabsf(pz - vz1) * INV_GS;
    float w[8] = {wx0*wy0*wz0, wx0*wy0*wz1, wx0*wy1*wz0, wx0*wy1*wz1,
                  wx1*wy0*wz0, wx1*wy0*wz1, wx1*wy1*wz0, wx1*wy1*wz1};

    const int RS = 16, SY = GRID_R1 * RS, SX = GRID_R1 * GRID_R1 * RS;
    const int off[8] = {0, RS, SY, SY + RS, SX, SX + RS, SX + SY, SX + SY + RS};
    int b = ((ci * GRID_R1 + cj) * GRID_R1 + ck) * 16 + sub;

    f32x4 acc = {0.f, 0.f, 0.f, 0.f};
#pragma unroll
    for (int c = 0; c < 8; ++c) acc += feats4[b + off[c]] * w[c];

    __builtin_nontemporal_store(acc, &out4[pt * 16 + sub]);
}

extern "C" void kernel_launch(void* const* d_in, const int* in_sizes, int n_in,
                              void* d_out, int out_size, void* d_ws, size_t ws_size,
                              hipStream_t stream) {
    const float* pos   = (const float*)d_in[0];
    const float* feats = (const float*)d_in[1];
    // d_in[2] (vertices) and d_in[3] (grid_indices) recomputed analytically.
    f32x4* out4 = (f32x4*)d_out;

    const int n  = in_sizes[0] / 3;                 // 500000
    const int n8 = (int)(FEAT_ELEMS / 8);           // 2,197,000
    const size_t featBytes = FEAT_ELEMS * sizeof(_Float16);  // 35.15 MB

    if (ws_size >= featBytes) {
        f16x8* feats16 = (f16x8*)d_ws;
        convert_kernel<<<(n8 + 255) / 256, 256, 0, stream>>>(
            (const f32x4*)feats, feats16, n8);
        const long long total = (long long)n * 8;   // 8 lanes per point
        trilerp_f16_kernel<<<(int)((total + 255) / 256), 256, 0, stream>>>(
            pos, feats16, out4, n);
    } else {
        const long long total = (long long)n * 16;
        trilerp_f32_kernel<<<(int)((total + 255) / 256), 256, 0, stream>>>(
            pos, (const f32x4*)feats, out4, n);
    }
}